// Round 1
// baseline (294.345 us; speedup 1.0000x reference)
//
#include <hip/hip_runtime.h>
#include <hip/hip_bf16.h>
#include <math.h>

// Problem constants (B=8, T=1024, C=32, F=256, D=128, K=512)
#define N_POS 8192      // B*T
#define D_DIM 128
#define K_DIM 512
#define C_DIM 32
#define F_DIM 256
#define KC    16        // codeword chunks for the NN search
#define KPER  32        // K_DIM / KC

// ---------------------------------------------------------------- reductions
__device__ __forceinline__ float block_reduce_256(float v) {
    __shared__ float sbuf[4];
    __syncthreads();                    // protect sbuf reuse across calls
#pragma unroll
    for (int off = 32; off > 0; off >>= 1) v += __shfl_down(v, off);
    const int lane = threadIdx.x & 63;
    const int w    = threadIdx.x >> 6;
    if (lane == 0) sbuf[w] = v;
    __syncthreads();
    return (threadIdx.x == 0) ? (sbuf[0] + sbuf[1] + sbuf[2] + sbuf[3]) : 0.f;
}

// ------------------------------------------------- kernel 1: transpose M->MT
// M: [D,K] row-major -> MT: [K,D] row-major (codeword rows contiguous)
__global__ void transpose_m(const float* __restrict__ M, float* __restrict__ MT) {
    const int idx = blockIdx.x * 256 + threadIdx.x;   // 65536 total
    const int k = idx >> 7;          // /128
    const int d = idx & 127;
    MT[idx] = M[d * K_DIM + k];
}

// ------------------------------------------- kernel 2: NN search (chunked K)
// grid (32, KC), block 256. Thread owns one (b,t) position; h[128] in VGPRs.
// MT rows are wave-uniform -> scalar loads; VALU does sub + add(abs).
__global__ __launch_bounds__(256, 2)
void nn_chunk(const float* __restrict__ H, const float* __restrict__ MT,
              float* __restrict__ pd, int* __restrict__ pi) {
    const int pos = blockIdx.x * 256 + threadIdx.x;
    const int b = pos >> 10;
    const int t = pos & 1023;
    const float* Hb = H + (b << 17) + t;   // H[b, d, t], stride T between d
    float h[D_DIM];
#pragma unroll
    for (int d = 0; d < D_DIM; ++d) h[d] = Hb[d << 10];

    const int kbase = blockIdx.y * KPER;
    float bestd = INFINITY;
    int   besti = kbase;
#pragma unroll 1
    for (int kk = 0; kk < KPER; ++kk) {
        const float* mk = MT + (size_t)(kbase + kk) * D_DIM;  // uniform address
        float a0 = 0.f, a1 = 0.f, a2 = 0.f, a3 = 0.f;
#pragma unroll
        for (int d = 0; d < D_DIM; d += 4) {
            a0 += fabsf(h[d]     - mk[d]);
            a1 += fabsf(h[d + 1] - mk[d + 1]);
            a2 += fabsf(h[d + 2] - mk[d + 2]);
            a3 += fabsf(h[d + 3] - mk[d + 3]);
        }
        const float dist = (a0 + a1) + (a2 + a3);
        if (dist < bestd) { bestd = dist; besti = kbase + kk; }  // first-min wins
    }
    pd[blockIdx.y * N_POS + pos] = bestd;
    pi[blockIdx.y * N_POS + pos] = besti;
}

// --------------------------- kernel 3: merge chunks + memory-loss SSE reduce
__global__ __launch_bounds__(256)
void merge_mem(const float* __restrict__ H, const float* __restrict__ MT,
               const float* __restrict__ pd, const int* __restrict__ pi,
               float* __restrict__ mem_accum) {
    const int pos = blockIdx.x * 256 + threadIdx.x;
    const int b = pos >> 10;
    const int t = pos & 1023;

    float bd = pd[pos];
    int   bi = pi[pos];
#pragma unroll 1
    for (int p = 1; p < KC; ++p) {
        const float d = pd[p * N_POS + pos];
        if (d < bd) { bd = d; bi = pi[p * N_POS + pos]; }  // strict <: lower chunk wins ties
    }

    const float* Hb = H + (b << 17) + t;
    const float* z  = MT + (size_t)bi * D_DIM;
    float s0 = 0.f, s1 = 0.f, s2 = 0.f, s3 = 0.f;
#pragma unroll
    for (int d = 0; d < D_DIM; d += 4) {
        const float e0 = Hb[(d)     << 10] - z[d];
        const float e1 = Hb[(d + 1) << 10] - z[d + 1];
        const float e2 = Hb[(d + 2) << 10] - z[d + 2];
        const float e3 = Hb[(d + 3) << 10] - z[d + 3];
        s0 += e0 * e0; s1 += e1 * e1; s2 += e2 * e2; s3 += e3 * e3;
    }
    const float r = block_reduce_256((s0 + s1) + (s2 + s3));
    if (threadIdx.x == 0) atomicAdd(mem_accum, r);
}

// ------------- kernel 4: Xhat rows, E = Xhat - X, loss_rec SSE, disc dot sum
// grid 32, block 256; thread owns one bt-row. W rows wave-uniform -> s_load.
__global__ __launch_bounds__(256, 2)
void xhat_e(const float* __restrict__ Hdec, const float* __restrict__ W,
            const float* __restrict__ X, const float* __restrict__ w_d,
            float* __restrict__ E, float* __restrict__ accum /*[0]=sse,[1]=dsum*/) {
    const int row = blockIdx.x * 256 + threadIdx.x;
    const float* hd = Hdec + (size_t)row * F_DIM;

    float acc[C_DIM];
#pragma unroll
    for (int c = 0; c < C_DIM; ++c) acc[c] = 0.f;

#pragma unroll 1
    for (int f0 = 0; f0 < F_DIM; f0 += 8) {
        float v[8];
#pragma unroll
        for (int j = 0; j < 8; ++j) v[j] = hd[f0 + j];
#pragma unroll
        for (int c = 0; c < C_DIM; ++c) {
            const float* wr = W + c * F_DIM + f0;   // uniform
#pragma unroll
            for (int j = 0; j < 8; ++j) acc[c] += v[j] * wr[j];
        }
    }

    float sse = 0.f, dp = 0.f;
    const float* xr = X + (size_t)row * C_DIM;
    float* er = E + (size_t)row * C_DIM;
#pragma unroll
    for (int c = 0; c < C_DIM; ++c) {
        const float e = acc[c] - xr[c];
        er[c] = e;
        sse += e * e;
        dp  += acc[c] * w_d[c];   // w_d uniform
    }
    const float r0 = block_reduce_256(sse);
    if (threadIdx.x == 0) atomicAdd(accum + 0, r0);
    const float r1 = block_reduce_256(dp);
    if (threadIdx.x == 0) atomicAdd(accum + 1, r1);
}

// --------------------- kernel 5: g_rec raw sums (E^T Hdec) and S[f] via atomics
// grid 128 (bt-chunks of 64), block 256 (thread = f). E rows uniform -> s_load.
__global__ __launch_bounds__(256, 2)
void grec_s(const float* __restrict__ Hdec, const float* __restrict__ E,
            float* __restrict__ g_rec, float* __restrict__ S) {
    const int f = threadIdx.x;
    const int bt0 = blockIdx.x * 64;
    float acc[C_DIM];
#pragma unroll
    for (int c = 0; c < C_DIM; ++c) acc[c] = 0.f;
    float sf = 0.f;
#pragma unroll 1
    for (int i = 0; i < 64; ++i) {
        const int bt = bt0 + i;
        const float hd = Hdec[(size_t)bt * F_DIM + f];   // coalesced
        sf += hd;
        const float* er = E + (size_t)bt * C_DIM;        // uniform
#pragma unroll
        for (int c = 0; c < C_DIM; ++c) acc[c] += er[c] * hd;
    }
#pragma unroll 1
    for (int c = 0; c < C_DIM; ++c) atomicAdd(&g_rec[c * F_DIM + f], acc[c]);
    atomicAdd(&S[f], sf);
}

// ------------------------- kernel 6: sum-of-squares of g_rec (raw) and S
__global__ __launch_bounds__(256)
void sq_reduce(const float* __restrict__ g_rec, const float* __restrict__ S,
               float* __restrict__ accum /*[3]=g2,[4]=s2*/) {
    if (blockIdx.x < 32) {
        const float v = g_rec[blockIdx.x * 256 + threadIdx.x];
        const float r = block_reduce_256(v * v);
        if (threadIdx.x == 0) atomicAdd(accum + 3, r);
    } else {
        const float v = S[threadIdx.x];
        const float r = block_reduce_256(v * v);
        if (threadIdx.x == 0) atomicAdd(accum + 4, r);
    }
}

// -------------------------------------------- kernel 7: assemble final scalar
__global__ void final_assemble(const float* __restrict__ w_d,
                               const float* __restrict__ accum,
                               float* __restrict__ out) {
    const int lane = threadIdx.x;
    float wd2 = (lane < C_DIM) ? w_d[lane] * w_d[lane] : 0.f;
#pragma unroll
    for (int off = 32; off > 0; off >>= 1) wd2 += __shfl_down(wd2, off);
    if (lane == 0) {
        const float loss_rec = accum[0] / 262144.f;            // /(B*T*C)
        const float loss_d   = -accum[1] / 8192.f;             // -mean over B*T
        const float loss_m   = 2.f * accum[2] / 1048576.f;     // 2*SSE/(B*D*T)
        const float ngrec    = (2.f / 262144.f) * sqrtf(accum[3]);
        const float ngd      = sqrtf(wd2 * accum[4]) / 8192.f;
        const float lmbda    = ngrec / (ngd + 1e-6f);
        out[0] = loss_rec + loss_m + lmbda * loss_d;           // ALPHA = 1
    }
}

// ---------------------------------------------------------------- launcher
extern "C" void kernel_launch(void* const* d_in, const int* in_sizes, int n_in,
                              void* d_out, int out_size, void* d_ws, size_t ws_size,
                              hipStream_t stream) {
    const float* X    = (const float*)d_in[0];   // [8,1024,32]
    const float* H    = (const float*)d_in[1];   // [8,128,1024]
    const float* M    = (const float*)d_in[2];   // [128,512]
    const float* Hdec = (const float*)d_in[3];   // [8,1024,256]
    const float* W    = (const float*)d_in[4];   // [32,256]
    const float* w_d  = (const float*)d_in[5];   // [32]

    float* ws    = (float*)d_ws;
    float* MT    = ws;                        // 65536  (256 KB)
    float* pd    = ws + 65536;                // 131072 (512 KB)
    int*   pi    = (int*)(ws + 196608);       // 131072 (512 KB)
    float* E     = ws + 327680;               // 262144 (1 MB)
    float* g_rec = ws + 589824;               // 8192
    float* S     = ws + 598016;               // 256
    float* accum = ws + 598272;               // 8 scalars
    // zero the atomic-accumulation region (ws is poisoned 0xAA every call)
    hipMemsetAsync(g_rec, 0, (8192 + 256 + 8) * sizeof(float), stream);

    transpose_m   <<<256,          256, 0, stream>>>(M, MT);
    nn_chunk      <<<dim3(32, KC), 256, 0, stream>>>(H, MT, pd, pi);
    merge_mem     <<<32,           256, 0, stream>>>(H, MT, pd, pi, accum + 2);
    xhat_e        <<<32,           256, 0, stream>>>(Hdec, W, X, w_d, E, accum);
    grec_s        <<<128,          256, 0, stream>>>(Hdec, E, g_rec, S);
    sq_reduce     <<<33,           256, 0, stream>>>(g_rec, S, accum);
    final_assemble<<<1,            64,  0, stream>>>(w_d, accum, (float*)d_out);
}

// Round 2
// 198.846 us; speedup vs baseline: 1.4803x; 1.4803x over previous
//
#include <hip/hip_runtime.h>
#include <hip/hip_bf16.h>
#include <math.h>

// Problem constants (B=8, T=1024, C=32, F=256, D=128, K=512)
#define N_POS 8192      // B*T
#define D_DIM 128
#define K_DIM 512
#define C_DIM 32
#define F_DIM 256
#define KC    32        // codeword chunks for the NN search
#define KPER  16        // K_DIM / KC
#define GREC_BLOCKS 128
#define GREC_COLS   8448   // 32*256 g_rec + 256 S

// ---------------------------------------------------------------- reductions
__device__ __forceinline__ float block_reduce_256(float v) {
    __shared__ float sbuf[4];
    __syncthreads();                    // protect sbuf reuse across calls
#pragma unroll
    for (int off = 32; off > 0; off >>= 1) v += __shfl_down(v, off);
    const int lane = threadIdx.x & 63;
    const int w    = threadIdx.x >> 6;
    if (lane == 0) sbuf[w] = v;
    __syncthreads();
    return (threadIdx.x == 0) ? (sbuf[0] + sbuf[1] + sbuf[2] + sbuf[3]) : 0.f;
}

// ------------------------------------------------- kernel 1: transpose M->MT
__global__ void transpose_m(const float* __restrict__ M, float* __restrict__ MT) {
    const int idx = blockIdx.x * 256 + threadIdx.x;   // 65536 total
    const int k = idx >> 7;          // /128
    const int d = idx & 127;
    MT[idx] = M[d * K_DIM + k];
}

// ------------------------------------------- kernel 2: NN search (chunked K)
// grid (32, KC), block 256. Thread owns one (b,t); h[128] in VGPRs.
// MT rows wave-uniform -> scalar loads. DO NOT change summation order
// (argmin tie behavior verified exact in R1).
__global__ __launch_bounds__(256, 2)
void nn_chunk(const float* __restrict__ H, const float* __restrict__ MT,
              float* __restrict__ pd, int* __restrict__ pi) {
    const int pos = blockIdx.x * 256 + threadIdx.x;
    const int b = pos >> 10;
    const int t = pos & 1023;
    const float* Hb = H + (b << 17) + t;   // H[b, d, t], stride T between d
    float h[D_DIM];
#pragma unroll
    for (int d = 0; d < D_DIM; ++d) h[d] = Hb[d << 10];

    const int kbase = blockIdx.y * KPER;
    float bestd = INFINITY;
    int   besti = kbase;
#pragma unroll 1
    for (int kk = 0; kk < KPER; ++kk) {
        const float* mk = MT + (size_t)(kbase + kk) * D_DIM;  // uniform address
        float a0 = 0.f, a1 = 0.f, a2 = 0.f, a3 = 0.f;
#pragma unroll
        for (int d = 0; d < D_DIM; d += 4) {
            a0 += fabsf(h[d]     - mk[d]);
            a1 += fabsf(h[d + 1] - mk[d + 1]);
            a2 += fabsf(h[d + 2] - mk[d + 2]);
            a3 += fabsf(h[d + 3] - mk[d + 3]);
        }
        const float dist = (a0 + a1) + (a2 + a3);
        if (dist < bestd) { bestd = dist; besti = kbase + kk; }  // first-min wins
    }
    pd[blockIdx.y * N_POS + pos] = bestd;
    pi[blockIdx.y * N_POS + pos] = besti;
}

// ------------------- kernel 3: merge chunk results + memory-loss SSE reduce
// grid (32 pos-blocks, 4 d-chunks). Each block rescans pd (cheap, coalesced),
// then accumulates SSE over its 32-d slice. Gather of z rows hits L2 (MT=256KB).
__global__ __launch_bounds__(256)
void mem_sse(const float* __restrict__ H, const float* __restrict__ MT,
             const float* __restrict__ pd, const int* __restrict__ pi,
             float* __restrict__ mem_accum) {
    const int pos = blockIdx.x * 256 + threadIdx.x;
    const int b = pos >> 10;
    const int t = pos & 1023;

    float bd = INFINITY;
    int   bp = 0;
#pragma unroll
    for (int p = 0; p < KC; ++p) {
        const float d = pd[p * N_POS + pos];
        if (d < bd) { bd = d; bp = p; }   // strict <: lowest chunk wins ties
    }
    const int bi = pi[bp * N_POS + pos];

    const int d0 = blockIdx.y * 32;
    const float* Hb = H + (b << 17) + t + (d0 << 10);
    const float* z  = MT + (size_t)bi * D_DIM + d0;
    float s0 = 0.f, s1 = 0.f, s2 = 0.f, s3 = 0.f;
#pragma unroll
    for (int d = 0; d < 32; d += 4) {
        const float e0 = Hb[(d)     << 10] - z[d];
        const float e1 = Hb[(d + 1) << 10] - z[d + 1];
        const float e2 = Hb[(d + 2) << 10] - z[d + 2];
        const float e3 = Hb[(d + 3) << 10] - z[d + 3];
        s0 += e0 * e0; s1 += e1 * e1; s2 += e2 * e2; s3 += e3 * e3;
    }
    const float r = block_reduce_256((s0 + s1) + (s2 + s3));
    if (threadIdx.x == 0) atomicAdd(mem_accum, r);
}

// ------------- kernel 4: Xhat, E = Xhat - X, loss_rec SSE, disc dot sum
// grid 256 blocks x 256 thr; thread = (c = tid&31, 4 rows). W staged in LDS
// with stride-260 rows (16B-aligned b128, 4-way bank alias ~19cyc < 32cyc VALU).
__global__ __launch_bounds__(256)
void xhat_e(const float* __restrict__ Hdec, const float* __restrict__ W,
            const float* __restrict__ X, const float* __restrict__ w_d,
            float* __restrict__ E, float* __restrict__ accum /*[0]=sse,[1]=dsum*/) {
    __shared__ float Wl[C_DIM * 260];
#pragma unroll
    for (int it = 0; it < 8; ++it) {                 // stage W: 8192 floats, float4
        const int i = it * 1024 + threadIdx.x * 4;
        const float4 v = *(const float4*)(W + i);
        *(float4*)(Wl + (i >> 8) * 260 + (i & 255)) = v;
    }
    __syncthreads();

    const int c    = threadIdx.x & 31;
    const int rg   = threadIdx.x >> 5;               // 0..7
    const int base = blockIdx.x * 32;
    const int r0 = base + rg, r1 = r0 + 8, r2 = r0 + 16, r3 = r0 + 24;

    float a0 = 0.f, a1 = 0.f, a2 = 0.f, a3 = 0.f;
#pragma unroll 4
    for (int f0 = 0; f0 < F_DIM; f0 += 4) {
        const float4 w4 = *(const float4*)(Wl + c * 260 + f0);
        const float4 h0 = *(const float4*)(Hdec + (size_t)r0 * F_DIM + f0);
        const float4 h1 = *(const float4*)(Hdec + (size_t)r1 * F_DIM + f0);
        const float4 h2 = *(const float4*)(Hdec + (size_t)r2 * F_DIM + f0);
        const float4 h3 = *(const float4*)(Hdec + (size_t)r3 * F_DIM + f0);
        a0 += h0.x * w4.x + h0.y * w4.y + h0.z * w4.z + h0.w * w4.w;
        a1 += h1.x * w4.x + h1.y * w4.y + h1.z * w4.z + h1.w * w4.w;
        a2 += h2.x * w4.x + h2.y * w4.y + h2.z * w4.z + h2.w * w4.w;
        a3 += h3.x * w4.x + h3.y * w4.y + h3.z * w4.z + h3.w * w4.w;
    }

    const float wd = w_d[c];
    float sse = 0.f, dp = 0.f;
    {
        const float e0 = a0 - X[(size_t)r0 * C_DIM + c];
        const float e1 = a1 - X[(size_t)r1 * C_DIM + c];
        const float e2 = a2 - X[(size_t)r2 * C_DIM + c];
        const float e3 = a3 - X[(size_t)r3 * C_DIM + c];
        E[(size_t)r0 * C_DIM + c] = e0;
        E[(size_t)r1 * C_DIM + c] = e1;
        E[(size_t)r2 * C_DIM + c] = e2;
        E[(size_t)r3 * C_DIM + c] = e3;
        sse = e0 * e0 + e1 * e1 + e2 * e2 + e3 * e3;
        dp  = (a0 + a1 + a2 + a3) * wd;
    }
    const float rA = block_reduce_256(sse);
    if (threadIdx.x == 0) atomicAdd(accum + 0, rA);
    const float rB = block_reduce_256(dp);
    if (threadIdx.x == 0) atomicAdd(accum + 1, rB);
}

// --------------- kernel 5: g_rec partials (E^T Hdec) and S[f], NO atomics
// grid 128 blocks x 64 rows; thread = f. E rows wave-uniform -> s_loads.
// Partials pp[block][8448]: [0,8192) g_rec (c*256+f), [8192,8448) S.
__global__ __launch_bounds__(256)
void grec_s(const float* __restrict__ Hdec, const float* __restrict__ E,
            float* __restrict__ pp) {
    const int f   = threadIdx.x;
    const int bt0 = blockIdx.x * 64;
    float acc[C_DIM];
#pragma unroll
    for (int c = 0; c < C_DIM; ++c) acc[c] = 0.f;
    float sf = 0.f;
#pragma unroll 1
    for (int i = 0; i < 64; ++i) {
        const int bt = bt0 + i;
        const float hd = Hdec[(size_t)bt * F_DIM + f];   // coalesced
        sf += hd;
        const float* er = E + (size_t)bt * C_DIM;        // uniform -> s_load
#pragma unroll
        for (int c = 0; c < C_DIM; ++c) acc[c] += er[c] * hd;
    }
    float* o = pp + (size_t)blockIdx.x * GREC_COLS;
#pragma unroll
    for (int c = 0; c < C_DIM; ++c) o[c * F_DIM + f] = acc[c];
    o[8192 + f] = sf;
}

// ---------- kernel 6: reduce partials across blocks, square, accumulate norms
// grid 33 x 256: blocks 0..31 -> sum g_rec^2 into accum[3]; block 32 -> S^2 -> accum[4]
__global__ __launch_bounds__(256)
void grec_reduce(const float* __restrict__ pp, float* __restrict__ accum) {
    const int col = blockIdx.x * 256 + threadIdx.x;   // 0..8447
    float s = 0.f;
#pragma unroll 4
    for (int p = 0; p < GREC_BLOCKS; ++p) s += pp[(size_t)p * GREC_COLS + col];
    const float r = block_reduce_256(s * s);
    if (threadIdx.x == 0) atomicAdd(accum + ((blockIdx.x == 32) ? 4 : 3), r);
}

// -------------------------------------------- kernel 7: assemble final scalar
__global__ void final_assemble(const float* __restrict__ w_d,
                               const float* __restrict__ accum,
                               float* __restrict__ out) {
    const int lane = threadIdx.x;
    float wd2 = (lane < C_DIM) ? w_d[lane] * w_d[lane] : 0.f;
#pragma unroll
    for (int off = 32; off > 0; off >>= 1) wd2 += __shfl_down(wd2, off);
    if (lane == 0) {
        const float loss_rec = accum[0] / 262144.f;            // /(B*T*C)
        const float loss_d   = -accum[1] / 8192.f;             // -mean over B*T
        const float loss_m   = 2.f * accum[2] / 1048576.f;     // 2*SSE/(B*D*T)
        const float ngrec    = (2.f / 262144.f) * sqrtf(accum[3]);
        const float ngd      = sqrtf(wd2 * accum[4]) / 8192.f;
        const float lmbda    = ngrec / (ngd + 1e-6f);
        out[0] = loss_rec + loss_m + lmbda * loss_d;           // ALPHA = 1
    }
}

// ---------------------------------------------------------------- launcher
extern "C" void kernel_launch(void* const* d_in, const int* in_sizes, int n_in,
                              void* d_out, int out_size, void* d_ws, size_t ws_size,
                              hipStream_t stream) {
    const float* X    = (const float*)d_in[0];   // [8,1024,32]
    const float* H    = (const float*)d_in[1];   // [8,128,1024]
    const float* M    = (const float*)d_in[2];   // [128,512]
    const float* Hdec = (const float*)d_in[3];   // [8,1024,256]
    const float* W    = (const float*)d_in[4];   // [32,256]
    const float* w_d  = (const float*)d_in[5];   // [32]

    float* ws    = (float*)d_ws;
    float* MT    = ws;                     // 65536 floats (256 KB)
    float* E     = ws + 65536;             // 262144 (1 MB)
    float* accum = ws + 327680;            // 16
    float* pd    = ws + 327696;            // KC*8192 = 262144
    int*   pi    = (int*)(ws + 589840);    // 262144
    // pp aliases pd/pi (dead after mem_sse): 128*8448 = 1081344 floats
    float* pp    = ws + 327696;            // total ws use ~5.7 MB

    hipMemsetAsync(accum, 0, 16 * sizeof(float), stream);

    transpose_m   <<<256,          256, 0, stream>>>(M, MT);
    nn_chunk      <<<dim3(32, KC), 256, 0, stream>>>(H, MT, pd, pi);
    mem_sse       <<<dim3(32, 4),  256, 0, stream>>>(H, MT, pd, pi, accum + 2);
    xhat_e        <<<256,          256, 0, stream>>>(Hdec, W, X, w_d, E, accum);
    grec_s        <<<GREC_BLOCKS,  256, 0, stream>>>(Hdec, E, pp);
    grec_reduce   <<<33,           256, 0, stream>>>(pp, accum);
    final_assemble<<<1,            64,  0, stream>>>(w_d, accum, (float*)d_out);
}

// Round 3
// 157.132 us; speedup vs baseline: 1.8732x; 1.2655x over previous
//
#include <hip/hip_runtime.h>
#include <hip/hip_bf16.h>
#include <math.h>

// Problem constants (B=8, T=1024, C=32, F=256, D=128, K=512)
#define N_POS 8192      // B*T
#define D_DIM 128
#define K_DIM 512
#define C_DIM 32
#define F_DIM 256
#define NKT   8         // k-tiles for NN (BK=64 each) -> chunk count for merge
#define BP    64        // positions per NN block
#define BK    64        // codewords per NN block
#define LDH   68        // padded d-major LDS row stride (floats)
#define GREC_BLOCKS 256
#define GREC_COLS   8448   // 32*256 g_rec + 256 S

// ---------------------------------------------------------------- reductions
__device__ __forceinline__ float block_reduce_256(float v) {
    __shared__ float sbuf[4];
    __syncthreads();                    // protect sbuf reuse across calls
#pragma unroll
    for (int off = 32; off > 0; off >>= 1) v += __shfl_down(v, off);
    const int lane = threadIdx.x & 63;
    const int w    = threadIdx.x >> 6;
    if (lane == 0) sbuf[w] = v;
    __syncthreads();
    return (threadIdx.x == 0) ? (sbuf[0] + sbuf[1] + sbuf[2] + sbuf[3]) : 0.f;
}

// ------------------------------------------------- kernel 1: transpose M->MT
// MT [K][D] used only by mem_sse's z-row gather (16B-contiguous per lane).
__global__ void transpose_m(const float* __restrict__ M, float* __restrict__ MT) {
    const int idx = blockIdx.x * 256 + threadIdx.x;   // 65536 total
    const int k = idx >> 7;          // /128
    const int d = idx & 127;
    MT[idx] = M[d * K_DIM + k];
}

// --------------------------- kernel 2: NN search, 64x64 tiled, LDS-resident
// grid (128 pos-tiles, NKT k-tiles), 256 thr. d-major LDS tiles (pad 68);
// thread owns 4 pos x 4 k accumulators. VALU-bound: 2 ds_read_b128 + 32 VALU
// per d. Tie semantics: k ascending everywhere, strict < keeps first.
__global__ __launch_bounds__(256, 2)
void nn_tiled(const float* __restrict__ H, const float* __restrict__ M,
              float* __restrict__ pd, int* __restrict__ pi) {
    __shared__ float hT[D_DIM * LDH];      // [d][pos]
    __shared__ float mT[D_DIM * LDH];      // [d][k]
    __shared__ float red_d[16 * BP];
    __shared__ int   red_i[16 * BP];

    const int pos0 = blockIdx.x * BP;      // 64-aligned; never crosses b
    const int b    = pos0 >> 10;
    const int t0   = pos0 & 1023;
    const int k0   = blockIdx.y * BK;
    const float* Hbase = H + (b << 17) + t0;     // + d*1024 + t

    // stage both tiles: 8 passes x 16 d-rows, float4-coalesced
    {
        const int tq = (threadIdx.x & 15) * 4;   // t/k offset within tile
        const int dq = threadIdx.x >> 4;         // 0..15
#pragma unroll
        for (int it = 0; it < 8; ++it) {
            const int d = it * 16 + dq;
            const float4 hv = *(const float4*)(Hbase + d * 1024 + tq);
            const float4 mv = *(const float4*)(M + d * K_DIM + k0 + tq);
            *(float4*)(hT + d * LDH + tq) = hv;
            *(float4*)(mT + d * LDH + tq) = mv;
        }
    }
    __syncthreads();

    const int p4 = (threadIdx.x & 15) * 4;   // pos quad
    const int q4 = (threadIdx.x >> 4) * 4;   // k quad
    float acc[4][4];
#pragma unroll
    for (int i = 0; i < 4; ++i)
#pragma unroll
        for (int j = 0; j < 4; ++j) acc[i][j] = 0.f;

#pragma unroll 4
    for (int d = 0; d < D_DIM; ++d) {
        const float4 hv = *(const float4*)(hT + d * LDH + p4);
        const float4 mv = *(const float4*)(mT + d * LDH + q4);
        acc[0][0] += fabsf(hv.x - mv.x); acc[0][1] += fabsf(hv.x - mv.y);
        acc[0][2] += fabsf(hv.x - mv.z); acc[0][3] += fabsf(hv.x - mv.w);
        acc[1][0] += fabsf(hv.y - mv.x); acc[1][1] += fabsf(hv.y - mv.y);
        acc[1][2] += fabsf(hv.y - mv.z); acc[1][3] += fabsf(hv.y - mv.w);
        acc[2][0] += fabsf(hv.z - mv.x); acc[2][1] += fabsf(hv.z - mv.y);
        acc[2][2] += fabsf(hv.z - mv.z); acc[2][3] += fabsf(hv.z - mv.w);
        acc[3][0] += fabsf(hv.w - mv.x); acc[3][1] += fabsf(hv.w - mv.y);
        acc[3][2] += fabsf(hv.w - mv.z); acc[3][3] += fabsf(hv.w - mv.w);
    }

    // per-thread argmin over its 4 k (ascending j -> lowest k wins ties)
#pragma unroll
    for (int i = 0; i < 4; ++i) {
        float bd = acc[i][0];
        int   bj = 0;
#pragma unroll
        for (int j = 1; j < 4; ++j)
            if (acc[i][j] < bd) { bd = acc[i][j]; bj = j; }
        red_d[(threadIdx.x >> 4) * BP + p4 + i] = bd;
        red_i[(threadIdx.x >> 4) * BP + p4 + i] = k0 + q4 + bj;
    }
    __syncthreads();

    // cross-thread: 16 k-quads ascending, strict <
    if (threadIdx.x < BP) {
        float bd = red_d[threadIdx.x];
        int   bi = red_i[threadIdx.x];
#pragma unroll
        for (int q = 1; q < 16; ++q) {
            const float d = red_d[q * BP + threadIdx.x];
            if (d < bd) { bd = d; bi = red_i[q * BP + threadIdx.x]; }
        }
        pd[blockIdx.y * N_POS + pos0 + threadIdx.x] = bd;
        pi[blockIdx.y * N_POS + pos0 + threadIdx.x] = bi;
    }
}

// ------------------- kernel 3: merge chunk results + memory-loss SSE reduce
// grid (32 pos-blocks, 8 d-slices of 16). z-row gather from MT per-lane float4.
__global__ __launch_bounds__(256)
void mem_sse(const float* __restrict__ H, const float* __restrict__ MT,
             const float* __restrict__ pd, const int* __restrict__ pi,
             float* __restrict__ mem_accum) {
    const int pos = blockIdx.x * 256 + threadIdx.x;
    const int b = pos >> 10;
    const int t = pos & 1023;

    float bd = INFINITY;
    int   bp = 0;
#pragma unroll
    for (int p = 0; p < NKT; ++p) {
        const float d = pd[p * N_POS + pos];
        if (d < bd) { bd = d; bp = p; }   // strict <: lowest chunk wins ties
    }
    const int bi = pi[bp * N_POS + pos];

    const int d0 = blockIdx.y * 16;
    const float* Hb = H + (b << 17) + t + (d0 << 10);
    const float* z  = MT + (size_t)bi * D_DIM + d0;
    const float4 z0 = *(const float4*)(z);
    const float4 z1 = *(const float4*)(z + 4);
    const float4 z2 = *(const float4*)(z + 8);
    const float4 z3 = *(const float4*)(z + 12);
    float s0 = 0.f, s1 = 0.f, s2 = 0.f, s3 = 0.f;
    {
        float e;
        e = Hb[0  << 10] - z0.x; s0 += e * e;
        e = Hb[1  << 10] - z0.y; s1 += e * e;
        e = Hb[2  << 10] - z0.z; s2 += e * e;
        e = Hb[3  << 10] - z0.w; s3 += e * e;
        e = Hb[4  << 10] - z1.x; s0 += e * e;
        e = Hb[5  << 10] - z1.y; s1 += e * e;
        e = Hb[6  << 10] - z1.z; s2 += e * e;
        e = Hb[7  << 10] - z1.w; s3 += e * e;
        e = Hb[8  << 10] - z2.x; s0 += e * e;
        e = Hb[9  << 10] - z2.y; s1 += e * e;
        e = Hb[10 << 10] - z2.z; s2 += e * e;
        e = Hb[11 << 10] - z2.w; s3 += e * e;
        e = Hb[12 << 10] - z3.x; s0 += e * e;
        e = Hb[13 << 10] - z3.y; s1 += e * e;
        e = Hb[14 << 10] - z3.z; s2 += e * e;
        e = Hb[15 << 10] - z3.w; s3 += e * e;
    }
    const float r = block_reduce_256((s0 + s1) + (s2 + s3));
    if (threadIdx.x == 0) atomicAdd(mem_accum, r);
}

// ------------- kernel 4: Xhat, E = Xhat - X, loss_rec SSE, disc dot sum
__global__ __launch_bounds__(256)
void xhat_e(const float* __restrict__ Hdec, const float* __restrict__ W,
            const float* __restrict__ X, const float* __restrict__ w_d,
            float* __restrict__ E, float* __restrict__ accum /*[0]=sse,[1]=dsum*/) {
    __shared__ float Wl[C_DIM * 260];
#pragma unroll
    for (int it = 0; it < 8; ++it) {                 // stage W: 8192 floats
        const int i = it * 1024 + threadIdx.x * 4;
        const float4 v = *(const float4*)(W + i);
        *(float4*)(Wl + (i >> 8) * 260 + (i & 255)) = v;
    }
    __syncthreads();

    const int c    = threadIdx.x & 31;
    const int rg   = threadIdx.x >> 5;               // 0..7
    const int base = blockIdx.x * 32;
    const int r0 = base + rg, r1 = r0 + 8, r2 = r0 + 16, r3 = r0 + 24;

    float a0 = 0.f, a1 = 0.f, a2 = 0.f, a3 = 0.f;
#pragma unroll 4
    for (int f0 = 0; f0 < F_DIM; f0 += 4) {
        const float4 w4 = *(const float4*)(Wl + c * 260 + f0);
        const float4 h0 = *(const float4*)(Hdec + (size_t)r0 * F_DIM + f0);
        const float4 h1 = *(const float4*)(Hdec + (size_t)r1 * F_DIM + f0);
        const float4 h2 = *(const float4*)(Hdec + (size_t)r2 * F_DIM + f0);
        const float4 h3 = *(const float4*)(Hdec + (size_t)r3 * F_DIM + f0);
        a0 += h0.x * w4.x + h0.y * w4.y + h0.z * w4.z + h0.w * w4.w;
        a1 += h1.x * w4.x + h1.y * w4.y + h1.z * w4.z + h1.w * w4.w;
        a2 += h2.x * w4.x + h2.y * w4.y + h2.z * w4.z + h2.w * w4.w;
        a3 += h3.x * w4.x + h3.y * w4.y + h3.z * w4.z + h3.w * w4.w;
    }

    const float wd = w_d[c];
    float sse, dp;
    {
        const float e0 = a0 - X[(size_t)r0 * C_DIM + c];
        const float e1 = a1 - X[(size_t)r1 * C_DIM + c];
        const float e2 = a2 - X[(size_t)r2 * C_DIM + c];
        const float e3 = a3 - X[(size_t)r3 * C_DIM + c];
        E[(size_t)r0 * C_DIM + c] = e0;
        E[(size_t)r1 * C_DIM + c] = e1;
        E[(size_t)r2 * C_DIM + c] = e2;
        E[(size_t)r3 * C_DIM + c] = e3;
        sse = e0 * e0 + e1 * e1 + e2 * e2 + e3 * e3;
        dp  = (a0 + a1 + a2 + a3) * wd;
    }
    const float rA = block_reduce_256(sse);
    if (threadIdx.x == 0) atomicAdd(accum + 0, rA);
    const float rB = block_reduce_256(dp);
    if (threadIdx.x == 0) atomicAdd(accum + 1, rB);
}

// --------------- kernel 5: g_rec partials (E^T Hdec) and S[f], NO atomics
// grid 256 blocks x 32 rows; thread = f. E rows wave-uniform -> s_loads.
__global__ __launch_bounds__(256)
void grec_s(const float* __restrict__ Hdec, const float* __restrict__ E,
            float* __restrict__ pp) {
    const int f   = threadIdx.x;
    const int bt0 = blockIdx.x * 32;
    float acc[C_DIM];
#pragma unroll
    for (int c = 0; c < C_DIM; ++c) acc[c] = 0.f;
    float sf = 0.f;
#pragma unroll 1
    for (int i = 0; i < 32; ++i) {
        const int bt = bt0 + i;
        const float hd = Hdec[(size_t)bt * F_DIM + f];   // coalesced
        sf += hd;
        const float* er = E + (size_t)bt * C_DIM;        // uniform -> s_load
#pragma unroll
        for (int c = 0; c < C_DIM; ++c) acc[c] += er[c] * hd;
    }
    float* o = pp + (size_t)blockIdx.x * GREC_COLS;
#pragma unroll
    for (int c = 0; c < C_DIM; ++c) o[c * F_DIM + f] = acc[c];
    o[8192 + f] = sf;
}

// ---------- kernel 6: reduce partials across blocks, square, accumulate norms
// grid 132 x 256: col = blockIdx*64 + (tid&63); 4 thread-groups split partials.
// Blocks 0..127 -> g_rec^2 (accum[3]); 128..131 -> S^2 (accum[4]).
__global__ __launch_bounds__(256)
void grec_reduce(const float* __restrict__ pp, float* __restrict__ accum) {
    const int col = blockIdx.x * 64 + (threadIdx.x & 63);
    const int pc  = threadIdx.x >> 6;                  // 0..3
    const float* base = pp + (size_t)(pc * 64) * GREC_COLS + col;
    float s = 0.f;
#pragma unroll 8
    for (int p = 0; p < 64; ++p) s += base[(size_t)p * GREC_COLS];
    __shared__ float red[4][64];
    red[pc][threadIdx.x & 63] = s;
    __syncthreads();
    if (threadIdx.x < 64) {
        const float tot = red[0][threadIdx.x] + red[1][threadIdx.x] +
                          red[2][threadIdx.x] + red[3][threadIdx.x];
        float v = tot * tot;
#pragma unroll
        for (int off = 32; off > 0; off >>= 1) v += __shfl_down(v, off);
        if (threadIdx.x == 0)
            atomicAdd(accum + ((blockIdx.x >= 128) ? 4 : 3), v);
    }
}

// -------------------------------------------- kernel 7: assemble final scalar
__global__ void final_assemble(const float* __restrict__ w_d,
                               const float* __restrict__ accum,
                               float* __restrict__ out) {
    const int lane = threadIdx.x;
    float wd2 = (lane < C_DIM) ? w_d[lane] * w_d[lane] : 0.f;
#pragma unroll
    for (int off = 32; off > 0; off >>= 1) wd2 += __shfl_down(wd2, off);
    if (lane == 0) {
        const float loss_rec = accum[0] / 262144.f;            // /(B*T*C)
        const float loss_d   = -accum[1] / 8192.f;             // -mean over B*T
        const float loss_m   = 2.f * accum[2] / 1048576.f;     // 2*SSE/(B*D*T)
        const float ngrec    = (2.f / 262144.f) * sqrtf(accum[3]);
        const float ngd      = sqrtf(wd2 * accum[4]) / 8192.f;
        const float lmbda    = ngrec / (ngd + 1e-6f);
        out[0] = loss_rec + loss_m + lmbda * loss_d;           // ALPHA = 1
    }
}

// ---------------------------------------------------------------- launcher
extern "C" void kernel_launch(void* const* d_in, const int* in_sizes, int n_in,
                              void* d_out, int out_size, void* d_ws, size_t ws_size,
                              hipStream_t stream) {
    const float* X    = (const float*)d_in[0];   // [8,1024,32]
    const float* H    = (const float*)d_in[1];   // [8,128,1024]
    const float* M    = (const float*)d_in[2];   // [128,512]
    const float* Hdec = (const float*)d_in[3];   // [8,1024,256]
    const float* W    = (const float*)d_in[4];   // [32,256]
    const float* w_d  = (const float*)d_in[5];   // [32]

    float* ws    = (float*)d_ws;
    float* MT    = ws;                      // 65536 floats
    float* E     = ws + 65536;              // 262144
    float* accum = ws + 327680;             // 16
    float* pd    = ws + 327696;             // NKT*8192 = 65536
    int*   pi    = (int*)(ws + 393232);     // 65536
    float* pp    = ws + 458768;             // 256*8448 = 2162688 (~10.5 MB total)

    hipMemsetAsync(accum, 0, 16 * sizeof(float), stream);

    transpose_m   <<<256,            256, 0, stream>>>(M, MT);
    nn_tiled      <<<dim3(128, NKT), 256, 0, stream>>>(H, M, pd, pi);
    mem_sse       <<<dim3(32, 8),    256, 0, stream>>>(H, MT, pd, pi, accum + 2);
    xhat_e        <<<256,            256, 0, stream>>>(Hdec, W, X, w_d, E, accum);
    grec_s        <<<GREC_BLOCKS,    256, 0, stream>>>(Hdec, E, pp);
    grec_reduce   <<<132,            256, 0, stream>>>(pp, accum);
    final_assemble<<<1,              64,  0, stream>>>(w_d, accum, (float*)d_out);
}